// Round 18
// baseline (353.502 us; speedup 1.0000x reference)
//
#include <hip/hip_runtime.h>
#include <math.h>

#define N_NODES 100000
#define N_EDGES 1600000
#define IN_DIM  500
#define HID     64
#define OUT_DIM 40
#define BN_EPS  1e-5f
#define SCAN_NB 98          // ceil(100000 / 1024)
#define NTILE   6250        // N_NODES / 16 (exact)

typedef _Float16 f16;
typedef __attribute__((ext_vector_type(2))) _Float16 f16x2;
typedef __attribute__((ext_vector_type(8))) _Float16 f16x8;
typedef __attribute__((ext_vector_type(4))) float f32x4;

static inline int cdiv(long a, int b) { return (int)((a + b - 1) / b); }

__device__ inline unsigned short f2h_bits(float f) {
    f16 h = (f16)f;
    return __builtin_bit_cast(unsigned short, h);
}
__device__ inline f16x2 bits2h2(unsigned int u) {
    return __builtin_bit_cast(f16x2, u);
}

// ---------------- integer in-degree ----------------
__global__ void k_count_deg(const int* __restrict__ ei, int* degi) {
    int e = blockIdx.x * 256 + threadIdx.x;
    if (e < N_EDGES) atomicAdd(&degi[ei[N_EDGES + e]], 1);
}

// ---------------- exclusive scan over (deg+1); also emits dis ----------------
__global__ void k_scan1(const int* __restrict__ degi, int* __restrict__ rowptr,
                        int* __restrict__ blocksum, float* __restrict__ dis) {
    __shared__ int sd[256];
    int tid = threadIdx.x;
    int base = blockIdx.x * 1024 + tid * 4;
    int v0 = (base + 0 < N_NODES) ? degi[base + 0] : -1;
    int v1 = (base + 1 < N_NODES) ? degi[base + 1] : -1;
    int v2 = (base + 2 < N_NODES) ? degi[base + 2] : -1;
    int v3 = (base + 3 < N_NODES) ? degi[base + 3] : -1;
    if (base + 0 < N_NODES) dis[base + 0] = rsqrtf((float)v0 + 1.0f);
    if (base + 1 < N_NODES) dis[base + 1] = rsqrtf((float)v1 + 1.0f);
    if (base + 2 < N_NODES) dis[base + 2] = rsqrtf((float)v2 + 1.0f);
    if (base + 3 < N_NODES) dis[base + 3] = rsqrtf((float)v3 + 1.0f);
    int w0 = v0 + 1, w1 = v1 + 1, w2 = v2 + 1, w3 = v3 + 1;   // deg+1 (0 if OOB)
    int s = w0 + w1 + w2 + w3;
    sd[tid] = s;
    __syncthreads();
    for (int off = 1; off < 256; off <<= 1) {
        int t = (tid >= off) ? sd[tid - off] : 0;
        __syncthreads();
        sd[tid] += t;
        __syncthreads();
    }
    int excl = sd[tid] - s;
    if (base + 0 < N_NODES) rowptr[base + 0] = excl;
    if (base + 1 < N_NODES) rowptr[base + 1] = excl + w0;
    if (base + 2 < N_NODES) rowptr[base + 2] = excl + w0 + w1;
    if (base + 3 < N_NODES) rowptr[base + 3] = excl + w0 + w1 + w2;
    if (tid == 255) blocksum[blockIdx.x] = sd[255];
}

__global__ void k_scan2(int* __restrict__ blocksum, int* __restrict__ blockbase) {
    __shared__ int sd[128];
    int tid = threadIdx.x;
    int v = (tid < SCAN_NB) ? blocksum[tid] : 0;
    sd[tid] = v;
    __syncthreads();
    for (int off = 1; off < 128; off <<= 1) {
        int t = (tid >= off) ? sd[tid - off] : 0;
        __syncthreads();
        sd[tid] += t;
        __syncthreads();
    }
    if (tid < SCAN_NB) blockbase[tid] = sd[tid] - v;
}

// scan3: finalize rowptr, write self-loop CSR entry + cursor=1, sentinel.
__global__ void k_scan3(int* __restrict__ rowptr, const int* __restrict__ blockbase,
                        const int* __restrict__ degi, int* __restrict__ cursor,
                        uint2* __restrict__ epack) {
    int add = blockbase[blockIdx.x];
    int base = blockIdx.x * 1024 + threadIdx.x * 4;
#pragma unroll
    for (int i = 0; i < 4; ++i) {
        int node = base + i;
        if (node < N_NODES) {
            int rp = rowptr[node] + add;
            rowptr[node] = rp;
            float d2 = 1.0f / (float)(degi[node] + 1);   // dis^2 exactly
            unsigned int hb = f2h_bits(d2);
            epack[rp] = make_uint2((unsigned int)(node * 128), (hb << 16) | hb);
            cursor[node] = 1;
        }
    }
    if (blockIdx.x == 0 && threadIdx.x == 0)
        rowptr[N_NODES] = N_EDGES + N_NODES;   // sentinel
}

// ---------------- CSR permute: group edges by dst, packed meta ----------------
__global__ void k_permute(const int* __restrict__ ei, const int* __restrict__ rowptr,
                          int* __restrict__ cursor, const float* __restrict__ dis,
                          uint2* __restrict__ epack) {
    int e = blockIdx.x * 256 + threadIdx.x;
    if (e >= N_EDGES) return;
    int s = ei[e];
    int d = ei[N_EDGES + e];
    int pos = rowptr[d] + atomicAdd(&cursor[d], 1);
    unsigned int hb = f2h_bits(dis[s] * dis[d]);
    epack[pos] = make_uint2((unsigned int)(s * 128), (hb << 16) | hb);
}

// ---------------- weight pack + BN fold (one dispatch) -----------------------
__device__ inline void convW_one(const float* W, unsigned short* wb,
                                 int idx, int K, int F) {
    int j    = idx & 7;
    int lane = (idx >> 3) & 63;
    int q    = idx >> 9;             // t*4 + nt
    int t    = q >> 2, nt = q & 3;
    int n = nt * 16 + (lane & 15);
    int k = t * 32 + ((lane >> 4) << 3) + j;
    float v = (k < K && n < F) ? W[(long)k * F + n] : 0.f;
    wb[idx] = f2h_bits(v);
}

__global__ void k_conv(const float* __restrict__ W1, const float* __restrict__ W2,
                       const float* __restrict__ W3,
                       unsigned short* __restrict__ wb1,
                       unsigned short* __restrict__ wb2,
                       unsigned short* __restrict__ wb3,
                       const float* __restrict__ b1, const float* __restrict__ g1,
                       const float* __restrict__ be1, const float* __restrict__ m1,
                       const float* __restrict__ v1,
                       const float* __restrict__ b2, const float* __restrict__ g2,
                       const float* __restrict__ be2, const float* __restrict__ m2,
                       const float* __restrict__ v2,
                       unsigned short* __restrict__ sc1,
                       unsigned short* __restrict__ sc2) {
    if (blockIdx.x == 160) {   // BN fold block
        int t = threadIdx.x;
        if (t < 128) {
            int c = t & 63;
            const float *b, *g, *be, *m, *v;
            unsigned short* sc;
            if (t < 64) { b = b1; g = g1; be = be1; m = m1; v = v1; sc = sc1; }
            else        { b = b2; g = g2; be = be2; m = m2; v = v2; sc = sc2; }
            float S = g[c] * rsqrtf(v[c] + BN_EPS);
            float C = (b[c] - m[c]) * S + be[c];
            sc[c]      = f2h_bits(S);
            sc[64 + c] = f2h_bits(C);
        }
        return;
    }
    int idx = blockIdx.x * 256 + threadIdx.x;   // 160*256 = 40960
    if (idx < 32768) {
        convW_one(W1, wb1, idx, IN_DIM, HID);
    } else if (idx < 36864) {
        convW_one(W2, wb2, idx - 32768, HID, HID);
    } else {
        convW_one(W3, wb3, idx - 36864, HID, OUT_DIM);
    }
}

// ---------------- fused layer-1: stage 16 rows of x in LDS, MFMA vs W1 -------
__global__ __launch_bounds__(256) void k_l1fused(
        const float* __restrict__ x,
        const unsigned short* __restrict__ wb,
        unsigned short* __restrict__ h) {
    __shared__ unsigned short l[16 * 520];
    const int rt = blockIdx.x;
    const int tid = threadIdx.x;

#pragma unroll
    for (int it = 0; it < 8; ++it) {
        int slot = it * 256 + tid;
        int row = slot >> 7, kq = slot & 127;
        float4 v = make_float4(0.f, 0.f, 0.f, 0.f);
        if (kq < 125)
            v = *reinterpret_cast<const float4*>(x + ((long)rt * 16 + row) * IN_DIM + kq * 4);
        unsigned int u0 = (unsigned int)f2h_bits(v.x) | ((unsigned int)f2h_bits(v.y) << 16);
        unsigned int u1 = (unsigned int)f2h_bits(v.z) | ((unsigned int)f2h_bits(v.w) << 16);
        *reinterpret_cast<uint2*>(&l[row * 520 + kq * 4]) = make_uint2(u0, u1);
    }
    __syncthreads();

    const int wid  = tid >> 6;
    const int lane = tid & 63;
    const int l15  = lane & 15;
    const int lhi  = lane >> 4;

    const f16x8* bp = reinterpret_cast<const f16x8*>(wb) + wid * 64 + lane;
    const unsigned short* arow = &l[l15 * 520 + lhi * 8];

    f32x4 acc = (f32x4){0.f, 0.f, 0.f, 0.f};
    f16x8 ca = *reinterpret_cast<const f16x8*>(arow);
    f16x8 cb = bp[0];

#pragma unroll
    for (int t = 0; t < 16; ++t) {
        f16x8 na, nb;
        if (t < 15) {
            na = *reinterpret_cast<const f16x8*>(arow + (t + 1) * 32);
            nb = bp[(t + 1) * 256];
        }
        acc = __builtin_amdgcn_mfma_f32_16x16x32_f16(ca, cb, acc, 0, 0, 0);
        if (t < 15) { ca = na; cb = nb; }
    }

#pragma unroll
    for (int rr = 0; rr < 4; ++rr) {
        long grow = (long)rt * 16 + lhi * 4 + rr;
        h[grow * 64 + wid * 16 + l15] = f2h_bits(acc[rr]);
    }
}

// ---------------- fused agg + BN/ReLU + GEMM --------------------------------
// Block = 16 nodes, 4 waves; wave w owns 4 nodes. Per segment, up to 4
// predicated gather rounds issued up-front (16 independent chains per wave),
// loop only for deg+1 > 32. Butterfly + folded BN/ReLU; 16x64 f16 LDS tile;
// MFMA vs packed W cols w*16..+15.
__global__ __launch_bounds__(256) void k_agg_gemm(
        const unsigned short* __restrict__ h_in, const int* __restrict__ rowptr,
        const uint2* __restrict__ epack, const unsigned short* __restrict__ sc,
        const unsigned short* __restrict__ wb, unsigned short* __restrict__ h_out) {
    __shared__ unsigned short st[16 * 80];
    const int base = blockIdx.x * 16;
    const int tid  = threadIdx.x;
    const int wid  = tid >> 6;
    const int lane = tid & 63;
    const int e8 = lane >> 3, c8 = lane & 7;
    const int node0 = base + wid * 4;

    int start[4], cnt[4];
    {
        int r0 = rowptr[node0 + 0], r1 = rowptr[node0 + 1], r2 = rowptr[node0 + 2];
        int r3 = rowptr[node0 + 3], r4 = rowptr[node0 + 4];
        start[0] = r0; cnt[0] = r1 - r0;
        start[1] = r1; cnt[1] = r2 - r1;
        start[2] = r2; cnt[2] = r3 - r2;
        start[3] = r3; cnt[3] = r4 - r3;
    }
    const char* hb = (const char*)h_in + c8 * 16;

    f16x2 a[4][4];
#pragma unroll
    for (int s = 0; s < 4; ++s)
#pragma unroll
        for (int i = 0; i < 4; ++i) a[s][i] = (f16x2)0;

    auto gath = [&](int s, int j) {
        int jj = j + e8;
        bool valid = jj < cnt[s];
        uint2 mv = epack[start[s] + (valid ? jj : 0)];
        f16x2 w2 = bits2h2(valid ? mv.y : 0u);
        uint4 hv = *(const uint4*)(hb + mv.x);
        a[s][0] += bits2h2(hv.x) * w2;
        a[s][1] += bits2h2(hv.y) * w2;
        a[s][2] += bits2h2(hv.z) * w2;
        a[s][3] += bits2h2(hv.w) * w2;
    };

#pragma unroll
    for (int s = 0; s < 4; ++s) {
        gath(s, 0);
        if (cnt[s] > 8)  gath(s, 8);
        if (cnt[s] > 16) gath(s, 16);
        if (cnt[s] > 24) gath(s, 24);
        for (int j = 32; j < cnt[s]; j += 8) gath(s, j);
    }

#pragma unroll
    for (int off = 8; off < 64; off <<= 1) {
#pragma unroll
        for (int s = 0; s < 4; ++s)
#pragma unroll
            for (int i = 0; i < 4; ++i) {
                unsigned int u = __builtin_bit_cast(unsigned int, a[s][i]);
                a[s][i] += bits2h2((unsigned int)__shfl_xor((int)u, off));
            }
    }

    if (e8 == 0) {
        uint4 Su = *(const uint4*)(sc + c8 * 8);
        uint4 Cu = *(const uint4*)(sc + 64 + c8 * 8);
        unsigned int sw[4] = {Su.x, Su.y, Su.z, Su.w};
        unsigned int cw[4] = {Cu.x, Cu.y, Cu.z, Cu.w};
#pragma unroll
        for (int s = 0; s < 4; ++s) {
            unsigned int u[4];
#pragma unroll
            for (int p = 0; p < 4; ++p) {
                f16x2 r = a[s][p] * bits2h2(sw[p]) + bits2h2(cw[p]);
                r[0] = r[0] > (f16)0 ? r[0] : (f16)0;
                r[1] = r[1] > (f16)0 ? r[1] : (f16)0;
                u[p] = __builtin_bit_cast(unsigned int, r);
            }
            int row = wid * 4 + s;
            *reinterpret_cast<uint4*>(&st[row * 80 + c8 * 8]) =
                make_uint4(u[0], u[1], u[2], u[3]);
        }
    }
    __syncthreads();

    // phase 2: 16x64 tile @ W cols wid*16..+15 (A row = l15, k = lhi*8 + t*32)
    const int l15 = lane & 15, lhi = lane >> 4;
    const unsigned short* arow = &st[l15 * 80 + lhi * 8];
    const f16x8* bp = reinterpret_cast<const f16x8*>(wb) + wid * 64 + lane;

    f32x4 acc = (f32x4){0.f, 0.f, 0.f, 0.f};
    f16x8 a0 = *reinterpret_cast<const f16x8*>(arow);
    f16x8 a1 = *reinterpret_cast<const f16x8*>(arow + 32);
    f16x8 b0 = bp[0];
    f16x8 b1 = bp[256];
    acc = __builtin_amdgcn_mfma_f32_16x16x32_f16(a0, b0, acc, 0, 0, 0);
    acc = __builtin_amdgcn_mfma_f32_16x16x32_f16(a1, b1, acc, 0, 0, 0);

#pragma unroll
    for (int rr = 0; rr < 4; ++rr) {
        long grow = (long)base + lhi * 4 + rr;
        h_out[grow * 64 + wid * 16 + l15] = f2h_bits(acc[rr]);
    }
}

// ---------------- pull aggregation + bias + log_softmax -----------------------
__global__ __launch_bounds__(256) void k_agg_lsm(
        const unsigned short* __restrict__ h, const int* __restrict__ rowptr,
        const uint2* __restrict__ epack,
        const float* __restrict__ bias, float* __restrict__ out) {
    int node = blockIdx.x * 4 + (threadIdx.x >> 6);
    if (node >= N_NODES) return;
    const int lane = threadIdx.x & 63;
    const int e8 = lane >> 3, c8 = lane & 7;
    const bool okc = c8 < 5;

    const int start = rowptr[node];
    const int cnt   = rowptr[node + 1] - start;   // includes self entry
    const uint2* ep = epack + start;
    const char*  hb = (const char*)h + c8 * 16;

    f16x2 a[4] = {(f16x2)0, (f16x2)0, (f16x2)0, (f16x2)0};

    auto batch = [&](int j) {
        int jj = j + e8;
        bool valid = jj < cnt;
        uint2 mv = ep[valid ? jj : 0];
        f16x2 w2 = bits2h2((valid && okc) ? mv.y : 0u);
        uint4 hv = *(const uint4*)(hb + (okc ? mv.x : 0u));
        a[0] += bits2h2(hv.x) * w2;
        a[1] += bits2h2(hv.y) * w2;
        a[2] += bits2h2(hv.z) * w2;
        a[3] += bits2h2(hv.w) * w2;
    };

    batch(0);
    if (cnt > 8)  batch(8);
    if (cnt > 16) batch(16);
    if (cnt > 24) batch(24);
    for (int j = 32; j < cnt; j += 8) batch(j);

#pragma unroll
    for (int off = 8; off < 64; off <<= 1) {
#pragma unroll
        for (int i = 0; i < 4; ++i) {
            unsigned int u = __builtin_bit_cast(unsigned int, a[i]);
            a[i] += bits2h2((unsigned int)__shfl_xor((int)u, off));
        }
    }

    float av[8] = {(float)a[0][0], (float)a[0][1], (float)a[1][0], (float)a[1][1],
                   (float)a[2][0], (float)a[2][1], (float)a[3][0], (float)a[3][1]};
    float vals[8];
    float mx = -INFINITY;
    if (okc) {
        float4 bb0 = *(const float4*)(bias + c8 * 8), bb1 = *(const float4*)(bias + c8 * 8 + 4);
        float bbv[8] = {bb0.x, bb0.y, bb0.z, bb0.w, bb1.x, bb1.y, bb1.z, bb1.w};
#pragma unroll
        for (int i = 0; i < 8; ++i) {
            vals[i] = av[i] + bbv[i];
            mx = fmaxf(mx, vals[i]);
        }
    }
#pragma unroll
    for (int o = 1; o < 8; o <<= 1) mx = fmaxf(mx, __shfl_xor(mx, o));
    float es = 0.f;
    if (okc) {
#pragma unroll
        for (int i = 0; i < 8; ++i) es += expf(vals[i] - mx);
    }
#pragma unroll
    for (int o = 1; o < 8; o <<= 1) es += __shfl_xor(es, o);
    float ls = logf(es);

    if (e8 == 0 && okc) {
        float* op = out + (long)node * 40 + c8 * 8;
        *(float4*)op = make_float4(vals[0] - mx - ls, vals[1] - mx - ls,
                                   vals[2] - mx - ls, vals[3] - mx - ls);
        *(float4*)(op + 4) = make_float4(vals[4] - mx - ls, vals[5] - mx - ls,
                                         vals[6] - mx - ls, vals[7] - mx - ls);
    }
}

extern "C" void kernel_launch(void* const* d_in, const int* in_sizes, int n_in,
                              void* d_out, int out_size, void* d_ws, size_t ws_size,
                              hipStream_t stream) {
    const float* x   = (const float*)d_in[0];
    const int*   ei  = (const int*)d_in[1];
    const float* W1  = (const float*)d_in[2];
    const float* b1  = (const float*)d_in[3];
    const float* g1  = (const float*)d_in[4];
    const float* be1 = (const float*)d_in[5];
    const float* m1  = (const float*)d_in[6];
    const float* v1  = (const float*)d_in[7];
    const float* W2  = (const float*)d_in[8];
    const float* b2  = (const float*)d_in[9];
    const float* g2  = (const float*)d_in[10];
    const float* be2 = (const float*)d_in[11];
    const float* m2  = (const float*)d_in[12];
    const float* v2  = (const float*)d_in[13];
    const float* W3  = (const float*)d_in[14];
    const float* b3  = (const float*)d_in[15];
    float* out = (float*)d_out;

    // workspace layout (units: floats from base; all 16B-aligned)
    float* ws        = (float*)d_ws;
    float* dis       = ws;                            // 100096
    int*   degi      = (int*)(ws + 100096);
    int*   cursor    = (int*)(ws + 200192);
    int*   rowptr    = (int*)(ws + 300288);           // 100096 (incl sentinel)
    int*   blocksum  = (int*)(ws + 400384);           // 128
    int*   blockbase = (int*)(ws + 400512);           // 128
    uint2* epack     = (uint2*)(ws + 400640);         // (E+N) uint2 = 3.4M floats
    unsigned short* h1 = (unsigned short*)(ws + 3800640);     // N*64 f16
    unsigned short* h2 = (unsigned short*)(ws + 7000640);
    unsigned short* h3 = (unsigned short*)(ws + 10200640);
    unsigned short* wb1 = (unsigned short*)(ws + 13400640);   // 32768 f16
    unsigned short* wb2 = (unsigned short*)(ws + 13417024);   // 4096
    unsigned short* wb3 = (unsigned short*)(ws + 13419072);   // 4096
    unsigned short* sc1 = (unsigned short*)(ws + 13421120);   // 128 f16
    unsigned short* sc2 = sc1 + 128;

    // ---- CSR build (self-loops included as explicit entries) ----
    hipMemsetAsync(degi, 0, 100096 * sizeof(int), stream);
    k_count_deg<<<cdiv(N_EDGES, 256), 256, 0, stream>>>(ei, degi);
    k_scan1<<<SCAN_NB, 256, 0, stream>>>(degi, rowptr, blocksum, dis);
    k_scan2<<<1, 128, 0, stream>>>(blocksum, blockbase);
    k_scan3<<<SCAN_NB, 256, 0, stream>>>(rowptr, blockbase, degi, cursor, epack);
    k_permute<<<cdiv(N_EDGES, 256), 256, 0, stream>>>(ei, rowptr, cursor, dis, epack);

    // ---- weight pack + BN fold ----
    k_conv<<<161, 256, 0, stream>>>(W1, W2, W3, wb1, wb2, wb3,
                                    b1, g1, be1, m1, v1, b2, g2, be2, m2, v2,
                                    sc1, sc2);

    // ---- layer 1: fused transpose+convert+GEMM (500 -> 64) ----
    k_l1fused<<<NTILE, 256, 0, stream>>>(x, wb1, h1);

    // ---- agg1 + BN1/ReLU + GEMM2 (fused) ----
    k_agg_gemm<<<NTILE, 256, 0, stream>>>(h1, rowptr, epack, sc1, wb2, h2);

    // ---- agg2 + BN2/ReLU + GEMM3 (fused; h3 64-wide, cols 40..63 zero) ----
    k_agg_gemm<<<NTILE, 256, 0, stream>>>(h2, rowptr, epack, sc2, wb3, h3);

    // ---- agg3 + bias + log_softmax ----
    k_agg_lsm<<<cdiv(N_NODES, 4), 256, 0, stream>>>(h3, rowptr, epack, b3, out);
}

// Round 19
// 335.988 us; speedup vs baseline: 1.0521x; 1.0521x over previous
//
#include <hip/hip_runtime.h>
#include <math.h>

#define N_NODES 100000
#define N_EDGES 1600000
#define IN_DIM  500
#define HID     64
#define OUT_DIM 40
#define BN_EPS  1e-5f
#define SCAN_NB 98          // ceil(100000 / 1024)
#define NTILE   6250        // N_NODES / 16 (exact)

typedef _Float16 f16;
typedef __attribute__((ext_vector_type(2))) _Float16 f16x2;
typedef __attribute__((ext_vector_type(8))) _Float16 f16x8;
typedef __attribute__((ext_vector_type(4))) float f32x4;

static inline int cdiv(long a, int b) { return (int)((a + b - 1) / b); }

__device__ inline unsigned short f2h_bits(float f) {
    f16 h = (f16)f;
    return __builtin_bit_cast(unsigned short, h);
}
__device__ inline f16x2 bits2h2(unsigned int u) {
    return __builtin_bit_cast(f16x2, u);
}

// ---------------- integer in-degree ----------------
__global__ void k_count_deg(const int* __restrict__ ei, int* degi) {
    int e = blockIdx.x * 256 + threadIdx.x;
    if (e < N_EDGES) atomicAdd(&degi[ei[N_EDGES + e]], 1);
}

// ---------------- exclusive scan over (deg+1); also emits dis ----------------
__global__ void k_scan1(const int* __restrict__ degi, int* __restrict__ rowptr,
                        int* __restrict__ blocksum, float* __restrict__ dis) {
    __shared__ int sd[256];
    int tid = threadIdx.x;
    int base = blockIdx.x * 1024 + tid * 4;
    int v0 = (base + 0 < N_NODES) ? degi[base + 0] : -1;
    int v1 = (base + 1 < N_NODES) ? degi[base + 1] : -1;
    int v2 = (base + 2 < N_NODES) ? degi[base + 2] : -1;
    int v3 = (base + 3 < N_NODES) ? degi[base + 3] : -1;
    if (base + 0 < N_NODES) dis[base + 0] = rsqrtf((float)v0 + 1.0f);
    if (base + 1 < N_NODES) dis[base + 1] = rsqrtf((float)v1 + 1.0f);
    if (base + 2 < N_NODES) dis[base + 2] = rsqrtf((float)v2 + 1.0f);
    if (base + 3 < N_NODES) dis[base + 3] = rsqrtf((float)v3 + 1.0f);
    int w0 = v0 + 1, w1 = v1 + 1, w2 = v2 + 1, w3 = v3 + 1;   // deg+1 (0 if OOB)
    int s = w0 + w1 + w2 + w3;
    sd[tid] = s;
    __syncthreads();
    for (int off = 1; off < 256; off <<= 1) {
        int t = (tid >= off) ? sd[tid - off] : 0;
        __syncthreads();
        sd[tid] += t;
        __syncthreads();
    }
    int excl = sd[tid] - s;
    if (base + 0 < N_NODES) rowptr[base + 0] = excl;
    if (base + 1 < N_NODES) rowptr[base + 1] = excl + w0;
    if (base + 2 < N_NODES) rowptr[base + 2] = excl + w0 + w1;
    if (base + 3 < N_NODES) rowptr[base + 3] = excl + w0 + w1 + w2;
    if (tid == 255) blocksum[blockIdx.x] = sd[255];
}

__global__ void k_scan2(int* __restrict__ blocksum, int* __restrict__ blockbase) {
    __shared__ int sd[128];
    int tid = threadIdx.x;
    int v = (tid < SCAN_NB) ? blocksum[tid] : 0;
    sd[tid] = v;
    __syncthreads();
    for (int off = 1; off < 128; off <<= 1) {
        int t = (tid >= off) ? sd[tid - off] : 0;
        __syncthreads();
        sd[tid] += t;
        __syncthreads();
    }
    if (tid < SCAN_NB) blockbase[tid] = sd[tid] - v;
}

// scan3: finalize rowptr, write self-loop CSR entry + cursor=1, sentinel.
__global__ void k_scan3(int* __restrict__ rowptr, const int* __restrict__ blockbase,
                        const int* __restrict__ degi, int* __restrict__ cursor,
                        uint2* __restrict__ epack) {
    int add = blockbase[blockIdx.x];
    int base = blockIdx.x * 1024 + threadIdx.x * 4;
#pragma unroll
    for (int i = 0; i < 4; ++i) {
        int node = base + i;
        if (node < N_NODES) {
            int rp = rowptr[node] + add;
            rowptr[node] = rp;
            float d2 = 1.0f / (float)(degi[node] + 1);   // dis^2 exactly
            unsigned int hb = f2h_bits(d2);
            epack[rp] = make_uint2((unsigned int)(node * 128), (hb << 16) | hb);
            cursor[node] = 1;
        }
    }
    if (blockIdx.x == 0 && threadIdx.x == 0)
        rowptr[N_NODES] = N_EDGES + N_NODES;   // sentinel
}

// ---------------- CSR permute: group edges by dst, packed meta ----------------
__global__ void k_permute(const int* __restrict__ ei, const int* __restrict__ rowptr,
                          int* __restrict__ cursor, const float* __restrict__ dis,
                          uint2* __restrict__ epack) {
    int e = blockIdx.x * 256 + threadIdx.x;
    if (e >= N_EDGES) return;
    int s = ei[e];
    int d = ei[N_EDGES + e];
    int pos = rowptr[d] + atomicAdd(&cursor[d], 1);
    unsigned int hb = f2h_bits(dis[s] * dis[d]);
    epack[pos] = make_uint2((unsigned int)(s * 128), (hb << 16) | hb);
}

// ---------------- weight pack (all 3 layers, one dispatch) -------------------
__device__ inline void convW_one(const float* W, unsigned short* wb,
                                 int idx, int K, int F) {
    int j    = idx & 7;
    int lane = (idx >> 3) & 63;
    int q    = idx >> 9;             // t*4 + nt
    int t    = q >> 2, nt = q & 3;
    int n = nt * 16 + (lane & 15);
    int k = t * 32 + ((lane >> 4) << 3) + j;
    float v = (k < K && n < F) ? W[(long)k * F + n] : 0.f;
    wb[idx] = f2h_bits(v);
}

__global__ void k_convall(const float* __restrict__ W1, const float* __restrict__ W2,
                          const float* __restrict__ W3,
                          unsigned short* __restrict__ wb1,
                          unsigned short* __restrict__ wb2,
                          unsigned short* __restrict__ wb3) {
    int idx = blockIdx.x * 256 + threadIdx.x;   // 160*256 = 40960
    if (idx < 32768) {
        convW_one(W1, wb1, idx, IN_DIM, HID);
    } else if (idx < 36864) {
        convW_one(W2, wb2, idx - 32768, HID, HID);
    } else {
        convW_one(W3, wb3, idx - 36864, HID, OUT_DIM);
    }
}

// ---------------- BN fold: S = g*rsqrt(v+eps); C = (b-m)*S + be  (f16) -------
__global__ void k_bnfold(const float* __restrict__ b1, const float* __restrict__ g1,
                         const float* __restrict__ be1, const float* __restrict__ m1,
                         const float* __restrict__ v1,
                         const float* __restrict__ b2, const float* __restrict__ g2,
                         const float* __restrict__ be2, const float* __restrict__ m2,
                         const float* __restrict__ v2,
                         unsigned short* __restrict__ sc1,
                         unsigned short* __restrict__ sc2) {
    int t = threadIdx.x;   // 0..127
    int c = t & 63;
    const float *b, *g, *be, *m, *v;
    unsigned short* sc;
    if (t < 64) { b = b1; g = g1; be = be1; m = m1; v = v1; sc = sc1; }
    else        { b = b2; g = g2; be = be2; m = m2; v = v2; sc = sc2; }
    float S = g[c] * rsqrtf(v[c] + BN_EPS);
    float C = (b[c] - m[c]) * S + be[c];
    sc[c]      = f2h_bits(S);
    sc[64 + c] = f2h_bits(C);
}

// ---------------- fused layer-1: stage 16 rows of x in LDS, MFMA vs W1 -------
__global__ __launch_bounds__(256) void k_l1fused(
        const float* __restrict__ x,
        const unsigned short* __restrict__ wb,
        unsigned short* __restrict__ h) {
    __shared__ unsigned short l[16 * 520];
    const int rt = blockIdx.x;
    const int tid = threadIdx.x;

#pragma unroll
    for (int it = 0; it < 8; ++it) {
        int slot = it * 256 + tid;
        int row = slot >> 7, kq = slot & 127;
        float4 v = make_float4(0.f, 0.f, 0.f, 0.f);
        if (kq < 125)
            v = *reinterpret_cast<const float4*>(x + ((long)rt * 16 + row) * IN_DIM + kq * 4);
        unsigned int u0 = (unsigned int)f2h_bits(v.x) | ((unsigned int)f2h_bits(v.y) << 16);
        unsigned int u1 = (unsigned int)f2h_bits(v.z) | ((unsigned int)f2h_bits(v.w) << 16);
        *reinterpret_cast<uint2*>(&l[row * 520 + kq * 4]) = make_uint2(u0, u1);
    }
    __syncthreads();

    const int wid  = tid >> 6;
    const int lane = tid & 63;
    const int l15  = lane & 15;
    const int lhi  = lane >> 4;

    const f16x8* bp = reinterpret_cast<const f16x8*>(wb) + wid * 64 + lane;
    const unsigned short* arow = &l[l15 * 520 + lhi * 8];

    f32x4 acc = (f32x4){0.f, 0.f, 0.f, 0.f};
    f16x8 ca = *reinterpret_cast<const f16x8*>(arow);
    f16x8 cb = bp[0];

#pragma unroll
    for (int t = 0; t < 16; ++t) {
        f16x8 na, nb;
        if (t < 15) {
            na = *reinterpret_cast<const f16x8*>(arow + (t + 1) * 32);
            nb = bp[(t + 1) * 256];
        }
        acc = __builtin_amdgcn_mfma_f32_16x16x32_f16(ca, cb, acc, 0, 0, 0);
        if (t < 15) { ca = na; cb = nb; }
    }

#pragma unroll
    for (int rr = 0; rr < 4; ++rr) {
        long grow = (long)rt * 16 + lhi * 4 + rr;
        h[grow * 64 + wid * 16 + l15] = f2h_bits(acc[rr]);
    }
}

// ---------------- fused agg + BN/ReLU + GEMM --------------------------------
// Block = 16 nodes, 4 waves. Phase 1: wave w aggregates its 4 nodes
// CONCURRENTLY (a[4][4] in regs, one j-loop over max cnt, all 4 segments
// predicated per iteration -> 4 independent meta->gather chains in flight).
// Butterfly + folded BN/ReLU once at the end; 16x64 f16 tile in LDS.
// Phase 2: wave w MFMAs the tile against packed W cols w*16..+15.
__global__ __launch_bounds__(256) void k_agg_gemm(
        const unsigned short* __restrict__ h_in, const int* __restrict__ rowptr,
        const uint2* __restrict__ epack, const unsigned short* __restrict__ sc,
        const unsigned short* __restrict__ wb, unsigned short* __restrict__ h_out) {
    __shared__ unsigned short st[16 * 80];
    const int base = blockIdx.x * 16;
    const int tid  = threadIdx.x;
    const int wid  = tid >> 6;
    const int lane = tid & 63;
    const int e8 = lane >> 3, c8 = lane & 7;
    const int node0 = base + wid * 4;

    int start[4], cnt[4];
    {
        int r0 = rowptr[node0 + 0], r1 = rowptr[node0 + 1], r2 = rowptr[node0 + 2];
        int r3 = rowptr[node0 + 3], r4 = rowptr[node0 + 4];
        start[0] = r0; cnt[0] = r1 - r0;
        start[1] = r1; cnt[1] = r2 - r1;
        start[2] = r2; cnt[2] = r3 - r2;
        start[3] = r3; cnt[3] = r4 - r3;
    }
    const char* hb = (const char*)h_in + c8 * 16;

    f16x2 a[4][4];
#pragma unroll
    for (int s = 0; s < 4; ++s)
#pragma unroll
        for (int i = 0; i < 4; ++i) a[s][i] = (f16x2)0;

    int maxc = max(max(cnt[0], cnt[1]), max(cnt[2], cnt[3]));

    for (int j = 0; j < maxc; j += 8) {
        int jj = j + e8;
#pragma unroll
        for (int s = 0; s < 4; ++s) {
            bool valid = jj < cnt[s];
            uint2 mv = epack[start[s] + (valid ? jj : 0)];
            f16x2 w2 = bits2h2(valid ? mv.y : 0u);
            uint4 hv = *(const uint4*)(hb + mv.x);
            a[s][0] += bits2h2(hv.x) * w2;
            a[s][1] += bits2h2(hv.y) * w2;
            a[s][2] += bits2h2(hv.z) * w2;
            a[s][3] += bits2h2(hv.w) * w2;
        }
    }

#pragma unroll
    for (int off = 8; off < 64; off <<= 1) {
#pragma unroll
        for (int s = 0; s < 4; ++s)
#pragma unroll
            for (int i = 0; i < 4; ++i) {
                unsigned int u = __builtin_bit_cast(unsigned int, a[s][i]);
                a[s][i] += bits2h2((unsigned int)__shfl_xor((int)u, off));
            }
    }

    if (e8 == 0) {
        uint4 Su = *(const uint4*)(sc + c8 * 8);
        uint4 Cu = *(const uint4*)(sc + 64 + c8 * 8);
        unsigned int sw[4] = {Su.x, Su.y, Su.z, Su.w};
        unsigned int cw[4] = {Cu.x, Cu.y, Cu.z, Cu.w};
#pragma unroll
        for (int s = 0; s < 4; ++s) {
            unsigned int u[4];
#pragma unroll
            for (int p = 0; p < 4; ++p) {
                f16x2 r = a[s][p] * bits2h2(sw[p]) + bits2h2(cw[p]);
                r[0] = r[0] > (f16)0 ? r[0] : (f16)0;
                r[1] = r[1] > (f16)0 ? r[1] : (f16)0;
                u[p] = __builtin_bit_cast(unsigned int, r);
            }
            int row = wid * 4 + s;
            *reinterpret_cast<uint4*>(&st[row * 80 + c8 * 8]) =
                make_uint4(u[0], u[1], u[2], u[3]);
        }
    }
    __syncthreads();

    // phase 2: 16x64 tile @ W cols wid*16..+15 (A row = l15, k = lhi*8 + t*32)
    const int l15 = lane & 15, lhi = lane >> 4;
    const unsigned short* arow = &st[l15 * 80 + lhi * 8];
    const f16x8* bp = reinterpret_cast<const f16x8*>(wb) + wid * 64 + lane;

    f32x4 acc = (f32x4){0.f, 0.f, 0.f, 0.f};
    f16x8 a0 = *reinterpret_cast<const f16x8*>(arow);
    f16x8 a1 = *reinterpret_cast<const f16x8*>(arow + 32);
    f16x8 b0 = bp[0];
    f16x8 b1 = bp[256];
    acc = __builtin_amdgcn_mfma_f32_16x16x32_f16(a0, b0, acc, 0, 0, 0);
    acc = __builtin_amdgcn_mfma_f32_16x16x32_f16(a1, b1, acc, 0, 0, 0);

#pragma unroll
    for (int rr = 0; rr < 4; ++rr) {
        long grow = (long)base + lhi * 4 + rr;
        h_out[grow * 64 + wid * 16 + l15] = f2h_bits(acc[rr]);
    }
}

// ---------------- pull aggregation + bias + log_softmax -----------------------
// c8>=5 lanes (cols 40..63, known zero) gather a fixed row-0 line (w=0):
// random traffic x5/8. Up to 4 gather rounds issued up-front (deg<=31 covered).
__global__ __launch_bounds__(256) void k_agg_lsm(
        const unsigned short* __restrict__ h, const int* __restrict__ rowptr,
        const uint2* __restrict__ epack,
        const float* __restrict__ bias, float* __restrict__ out) {
    int node = blockIdx.x * 4 + (threadIdx.x >> 6);
    if (node >= N_NODES) return;
    const int lane = threadIdx.x & 63;
    const int e8 = lane >> 3, c8 = lane & 7;
    const bool okc = c8 < 5;

    const int start = rowptr[node];
    const int cnt   = rowptr[node + 1] - start;   // includes self entry
    const uint2* ep = epack + start;
    const char*  hb = (const char*)h + c8 * 16;

    f16x2 a[4] = {(f16x2)0, (f16x2)0, (f16x2)0, (f16x2)0};

    auto batch = [&](int j) {
        int jj = j + e8;
        bool valid = jj < cnt;
        uint2 mv = ep[valid ? jj : 0];
        f16x2 w2 = bits2h2((valid && okc) ? mv.y : 0u);
        uint4 hv = *(const uint4*)(hb + (okc ? mv.x : 0u));
        a[0] += bits2h2(hv.x) * w2;
        a[1] += bits2h2(hv.y) * w2;
        a[2] += bits2h2(hv.z) * w2;
        a[3] += bits2h2(hv.w) * w2;
    };

    // up to 4 rounds in flight (covers deg+1 <= 32; loop handles the rest)
    batch(0);
    if (cnt > 8)  batch(8);
    if (cnt > 16) batch(16);
    if (cnt > 24) batch(24);
    for (int j = 32; j < cnt; j += 8) batch(j);

#pragma unroll
    for (int off = 8; off < 64; off <<= 1) {
#pragma unroll
        for (int i = 0; i < 4; ++i) {
            unsigned int u = __builtin_bit_cast(unsigned int, a[i]);
            a[i] += bits2h2((unsigned int)__shfl_xor((int)u, off));
        }
    }

    float av[8] = {(float)a[0][0], (float)a[0][1], (float)a[1][0], (float)a[1][1],
                   (float)a[2][0], (float)a[2][1], (float)a[3][0], (float)a[3][1]};
    float vals[8];
    float mx = -INFINITY;
    if (okc) {
        float4 bb0 = *(const float4*)(bias + c8 * 8), bb1 = *(const float4*)(bias + c8 * 8 + 4);
        float bbv[8] = {bb0.x, bb0.y, bb0.z, bb0.w, bb1.x, bb1.y, bb1.z, bb1.w};
#pragma unroll
        for (int i = 0; i < 8; ++i) {
            vals[i] = av[i] + bbv[i];
            mx = fmaxf(mx, vals[i]);
        }
    }
#pragma unroll
    for (int o = 1; o < 8; o <<= 1) mx = fmaxf(mx, __shfl_xor(mx, o));
    float es = 0.f;
    if (okc) {
#pragma unroll
        for (int i = 0; i < 8; ++i) es += expf(vals[i] - mx);
    }
#pragma unroll
    for (int o = 1; o < 8; o <<= 1) es += __shfl_xor(es, o);
    float ls = logf(es);

    if (e8 == 0 && okc) {
        float* op = out + (long)node * 40 + c8 * 8;
        *(float4*)op = make_float4(vals[0] - mx - ls, vals[1] - mx - ls,
                                   vals[2] - mx - ls, vals[3] - mx - ls);
        *(float4*)(op + 4) = make_float4(vals[4] - mx - ls, vals[5] - mx - ls,
                                         vals[6] - mx - ls, vals[7] - mx - ls);
    }
}

extern "C" void kernel_launch(void* const* d_in, const int* in_sizes, int n_in,
                              void* d_out, int out_size, void* d_ws, size_t ws_size,
                              hipStream_t stream) {
    const float* x   = (const float*)d_in[0];
    const int*   ei  = (const int*)d_in[1];
    const float* W1  = (const float*)d_in[2];
    const float* b1  = (const float*)d_in[3];
    const float* g1  = (const float*)d_in[4];
    const float* be1 = (const float*)d_in[5];
    const float* m1  = (const float*)d_in[6];
    const float* v1  = (const float*)d_in[7];
    const float* W2  = (const float*)d_in[8];
    const float* b2  = (const float*)d_in[9];
    const float* g2  = (const float*)d_in[10];
    const float* be2 = (const float*)d_in[11];
    const float* m2  = (const float*)d_in[12];
    const float* v2  = (const float*)d_in[13];
    const float* W3  = (const float*)d_in[14];
    const float* b3  = (const float*)d_in[15];
    float* out = (float*)d_out;

    // workspace layout (units: floats from base; all 16B-aligned)
    float* ws        = (float*)d_ws;
    float* dis       = ws;                            // 100096
    int*   degi      = (int*)(ws + 100096);
    int*   cursor    = (int*)(ws + 200192);
    int*   rowptr    = (int*)(ws + 300288);           // 100096 (incl sentinel)
    int*   blocksum  = (int*)(ws + 400384);           // 128
    int*   blockbase = (int*)(ws + 400512);           // 128
    uint2* epack     = (uint2*)(ws + 400640);         // (E+N) uint2 = 3.4M floats
    unsigned short* h1 = (unsigned short*)(ws + 3800640);     // N*64 f16
    unsigned short* h2 = (unsigned short*)(ws + 7000640);
    unsigned short* h3 = (unsigned short*)(ws + 10200640);
    unsigned short* wb1 = (unsigned short*)(ws + 13400640);   // 32768 f16
    unsigned short* wb2 = (unsigned short*)(ws + 13417024);   // 4096
    unsigned short* wb3 = (unsigned short*)(ws + 13419072);   // 4096
    unsigned short* sc1 = (unsigned short*)(ws + 13421120);   // 128 f16
    unsigned short* sc2 = sc1 + 128;

    // ---- CSR build (self-loops included as explicit entries) ----
    hipMemsetAsync(degi, 0, 100096 * sizeof(int), stream);
    k_count_deg<<<cdiv(N_EDGES, 256), 256, 0, stream>>>(ei, degi);
    k_scan1<<<SCAN_NB, 256, 0, stream>>>(degi, rowptr, blocksum, dis);
    k_scan2<<<1, 128, 0, stream>>>(blocksum, blockbase);
    k_scan3<<<SCAN_NB, 256, 0, stream>>>(rowptr, blockbase, degi, cursor, epack);
    k_permute<<<cdiv(N_EDGES, 256), 256, 0, stream>>>(ei, rowptr, cursor, dis, epack);

    // ---- weight pack + BN fold ----
    k_convall<<<160, 256, 0, stream>>>(W1, W2, W3, wb1, wb2, wb3);
    k_bnfold<<<1, 128, 0, stream>>>(b1, g1, be1, m1, v1, b2, g2, be2, m2, v2, sc1, sc2);

    const int agg_grid = cdiv(N_NODES, 4);

    // ---- layer 1: fused transpose+convert+GEMM (500 -> 64) ----
    k_l1fused<<<NTILE, 256, 0, stream>>>(x, wb1, h1);

    // ---- agg1 + BN1/ReLU + GEMM2 (fused) ----
    k_agg_gemm<<<NTILE, 256, 0, stream>>>(h1, rowptr, epack, sc1, wb2, h2);

    // ---- agg2 + BN2/ReLU + GEMM3 (fused; h3 64-wide, cols 40..63 zero) ----
    k_agg_gemm<<<NTILE, 256, 0, stream>>>(h2, rowptr, epack, sc2, wb3, h3);

    // ---- agg3 + bias + log_softmax ----
    k_agg_lsm<<<agg_grid, 256, 0, stream>>>(h3, rowptr, epack, b3, out);
}